// Round 10
// baseline (2119.420 us; speedup 1.0000x reference)
//
#include <hip/hip_runtime.h>

// Problem constants
#define B_   256
#define T_   512
#define E_   200
#define H_   100
#define H3_  300
#define NC_  5

#define WSTRIDE 304   // k_embgemm W_lds row stride (floats)
#define RSTR   108    // scan W row stride in dwords: 12l mod 32 -> 8 disjoint
                      // 4-bank windows -> conflict-free b128 at 128 B/cyc

__device__ __forceinline__ void fma4(float4& acc, float a, const float4& w) {
    acc.x = fmaf(a, w.x, acc.x);
    acc.y = fmaf(a, w.y, acc.y);
    acc.z = fmaf(a, w.z, acc.z);
    acc.w = fmaf(a, w.w, acc.w);
}

// Light barrier: drain LDS ops only (NOT global/vmcnt), then raw s_barrier.
// __syncthreads() would emit s_waitcnt vmcnt(0) and put HBM store/prefetch
// latency on the scan critical path every step.
__device__ __forceinline__ void ldsbar() {
    asm volatile("s_waitcnt lgkmcnt(0)" ::: "memory");
    __builtin_amdgcn_s_barrier();
    __builtin_amdgcn_sched_barrier(0);
}

// ---------------------------------------------------------------------------
// T0: pack weights: W_ihT[k][j] = W_ih[j][k]  (200x300)
//     wcat[k][j]: j<100 -> W_ti[j][k]; j==100 -> W_lgr[0][k]; else 0  (100x104)
// ---------------------------------------------------------------------------
__global__ void k_pack(const float* __restrict__ W_ih, const float* __restrict__ W_ti,
                       const float* __restrict__ W_lgr,
                       float* __restrict__ wT, float* __restrict__ wcat) {
    int idx = blockIdx.x * 256 + threadIdx.x;
    if (idx < E_ * H3_) {
        int k = idx / H3_, j = idx - k * H3_;
        wT[idx] = W_ih[j * E_ + k];
    }
    int i2 = idx - E_ * H3_;
    if (i2 >= 0 && i2 < H_ * 104) {
        int k = i2 / 104, j = i2 - k * 104;
        float v = 0.0f;
        if (j < H_) v = W_ti[j * H_ + k];
        else if (j == H_) v = W_lgr[k];
        wcat[i2] = v;
    }
}

// ---------------------------------------------------------------------------
// A: xp[row][j] = scale(row) * dot(emb[txt[row]], W_ih[j]) + b_ih[j]
// float4 staging, W double-buffered in 16-k-row tiles with register prefetch
// (1 light barrier/iter), parallel row-norm. ~69 KB LDS -> 2 blk/CU.
// ---------------------------------------------------------------------------
__global__ __launch_bounds__(320) void k_embgemm(
        const int* __restrict__ txt, const float* __restrict__ emb,
        const float* __restrict__ wT, const float* __restrict__ b_ih,
        float* __restrict__ xp) {
    __shared__ __align__(16) float A_lds[E_ * 36];            // 28.8 KB [k][r]
    __shared__ __align__(16) float W_lds[2][16 * WSTRIDE];    // 38.9 KB [buf][kk][j]
    __shared__ float pp_lds[10][32];
    __shared__ float scale_lds[32];

    int tid = threadIdx.x;
    int base = blockIdx.x * 32;

    // ---- stage A: 32 rows x 50 float4, transpose into [k][r] (stride 36)
#pragma unroll
    for (int L = 0; L < 5; ++L) {
        int q = tid + 320 * L;            // 0..1599
        int r = q / 50, k4 = q % 50;
        int row = txt[base + r];
        float4 v = ((const float4*)(emb + (size_t)row * E_))[k4];
        int k = k4 * 4;
        A_lds[(k + 0) * 36 + r] = v.x;
        A_lds[(k + 1) * 36 + r] = v.y;
        A_lds[(k + 2) * 36 + r] = v.z;
        A_lds[(k + 3) * 36 + r] = v.w;
    }
    // ---- stage W tile 0 (k rows 0..15): 1200 float4
#pragma unroll
    for (int L = 0; L < 4; ++L) {
        int f = tid + 320 * L;
        if (f < 16 * 75) {
            int kl = f / 75, j4 = f % 75;
            float4 v = ((const float4*)wT)[kl * 75 + j4];
            *(float4*)&W_lds[0][kl * WSTRIDE + j4 * 4] = v;
        }
    }
    __syncthreads();

    // ---- parallel row norms: 10 k-slices x 32 rows
    {
        int r = tid % 32, s = tid / 32;   // s in 0..9
        float ss = 0.f;
        for (int k = s * 20; k < s * 20 + 20; ++k) {
            float v = A_lds[k * 36 + r];
            ss = fmaf(v, v, ss);
        }
        pp_lds[s][r] = ss;
    }
    __syncthreads();
    if (tid < 32) {
        float ss = 0.f;
#pragma unroll
        for (int s = 0; s < 10; ++s) ss += pp_lds[s][tid];
        float n = sqrtf(ss);
        scale_lds[tid] = (n > 1.0f) ? (1.0f / (n + 1e-7f)) : 1.0f;
    }

    int c = tid % 80, g = tid / 80;
    float4 acc[8];
#pragma unroll
    for (int i = 0; i < 8; ++i) acc[i] = make_float4(0.f, 0.f, 0.f, 0.f);

    const int NT = 13;  // 12 tiles of 16 k-rows + 1 tile of 8
    for (int ic = 0; ic < NT; ++ic) {
        int KC = (ic == 12) ? 8 : 16;
        int cur = ic & 1;

        // prefetch next W tile into registers (in flight during compute)
        float4 pf0, pf1, pf2, pf3;
        int nKC = 0;
        if (ic + 1 < NT) {
            nKC = (ic + 1 == 12) ? 8 : 16;
            const float4* src = ((const float4*)wT) + (ic + 1) * 16 * 75;
            int f0 = tid;
            if (f0 < nKC * 75) pf0 = src[f0];
            int f1 = tid + 320;
            if (f1 < nKC * 75) pf1 = src[f1];
            int f2 = tid + 640;
            if (f2 < nKC * 75) pf2 = src[f2];
            int f3 = tid + 960;
            if (f3 < nKC * 75) pf3 = src[f3];
        }

        if (c < 75) {
            for (int kk = 0; kk < KC; ++kk) {
                int k = ic * 16 + kk;
                float4 wv = *(const float4*)&W_lds[cur][kk * WSTRIDE + c * 4];
                float4 a0 = *(const float4*)&A_lds[k * 36 + g * 8];
                float4 a1 = *(const float4*)&A_lds[k * 36 + g * 8 + 4];
                fma4(acc[0], a0.x, wv); fma4(acc[1], a0.y, wv);
                fma4(acc[2], a0.z, wv); fma4(acc[3], a0.w, wv);
                fma4(acc[4], a1.x, wv); fma4(acc[5], a1.y, wv);
                fma4(acc[6], a1.z, wv); fma4(acc[7], a1.w, wv);
            }
        }

        // write prefetched tile to the alternate buffer
        if (ic + 1 < NT) {
            int f0 = tid;
            if (f0 < nKC * 75) *(float4*)&W_lds[cur ^ 1][(f0 / 75) * WSTRIDE + (f0 % 75) * 4] = pf0;
            int f1 = tid + 320;
            if (f1 < nKC * 75) *(float4*)&W_lds[cur ^ 1][(f1 / 75) * WSTRIDE + (f1 % 75) * 4] = pf1;
            int f2 = tid + 640;
            if (f2 < nKC * 75) *(float4*)&W_lds[cur ^ 1][(f2 / 75) * WSTRIDE + (f2 % 75) * 4] = pf2;
            int f3 = tid + 960;
            if (f3 < nKC * 75) *(float4*)&W_lds[cur ^ 1][(f3 / 75) * WSTRIDE + (f3 % 75) * 4] = pf3;
        }
        ldsbar();
    }

    if (c < 75) {
        float4 bv = *(const float4*)&b_ih[c * 4];
#pragma unroll
        for (int rr = 0; rr < 8; ++rr) {
            int r = g * 8 + rr;
            float s = scale_lds[r];
            float4 res;
            res.x = fmaf(acc[rr].x, s, bv.x);
            res.y = fmaf(acc[rr].y, s, bv.y);
            res.z = fmaf(acc[rr].z, s, bv.z);
            res.w = fmaf(acc[rr].w, s, bv.w);
            *(float4*)&xp[(size_t)(base + r) * H3_ + c * 4] = res;
        }
    }
}

// ---------------------------------------------------------------------------
// B: GRU scan. 1 block per batch row, 320 threads (5 waves).
// W_hh lives in LDS ([300][RSTR] fp32, 129.6 KB, conflict-free stride):
// per-thread register demand ~25 -> spill impossible (the RA fight of rounds
// 1-9 is over). Thread j<300 computes its full row dot (25 W b128 + 25
// broadcast h b128); hp roundtrip; two light barriers/step; rnn store and
// x prefetch stay in flight across barriers.
// ---------------------------------------------------------------------------
__global__ __launch_bounds__(320, 1)
void k_gru(
        const float* __restrict__ xp, const float* __restrict__ W_hh,
        const float* __restrict__ b_hh, float* __restrict__ rnn) {
    __shared__ __align__(16) float Wl[H3_ * RSTR];   // 129.6 KB
    __shared__ __align__(16) float h_lds[104];
    __shared__ float hp_lds[H3_];

    int tid = threadIdx.x;
    int b = blockIdx.x;

    // stage W_hh -> LDS (7500 float4)
    for (int idx = tid; idx < 7500; idx += 320) {
        int j = idx / 25, q = idx - j * 25;
        float4 v = ((const float4*)(W_hh + (size_t)j * H_))[q];
        *(float4*)&Wl[j * RSTR + q * 4] = v;
    }

    float bhr = 0.f, bhz = 0.f, bhn = 0.f;
    if (tid < H_) { bhr = b_hh[tid]; bhz = b_hh[H_ + tid]; bhn = b_hh[2 * H_ + tid]; }
    if (tid < 104) h_lds[tid] = 0.0f;
    float hown = 0.0f;  // thread tid<100 keeps its own h[tid]

    const float* xpb = xp + (size_t)b * T_ * H3_;
    float* rnnb = rnn + (size_t)b * T_ * H_;
    float xr = 0.f, xz = 0.f, xn = 0.f;
    if (tid < H_) { xr = xpb[tid]; xz = xpb[H_ + tid]; xn = xpb[2 * H_ + tid]; }
    __syncthreads();

    const float* wr = &Wl[tid * RSTR];
    for (int t = 0; t < T_; ++t) {
        if (tid < H3_) {
            float a0 = 0.f, a1 = 0.f, a2 = 0.f, a3 = 0.f;
#pragma unroll
            for (int q = 0; q < 25; ++q) {
                float4 wv = *(const float4*)&wr[q * 4];       // conflict-free
                float4 hv = *(const float4*)&h_lds[q * 4];    // broadcast
                a0 = fmaf(wv.x, hv.x, a0);
                a1 = fmaf(wv.y, hv.y, a1);
                a2 = fmaf(wv.z, hv.z, a2);
                a3 = fmaf(wv.w, hv.w, a3);
            }
            hp_lds[tid] = (a0 + a1) + (a2 + a3);
        }
        // prefetch next step's x (stays in flight across the barriers)
        float nxr = 0.f, nxz = 0.f, nxn = 0.f;
        if (tid < H_ && t + 1 < T_) {
            const float* xq = xpb + (size_t)(t + 1) * H3_;
            nxr = xq[tid]; nxz = xq[H_ + tid]; nxn = xq[2 * H_ + tid];
        }
        ldsbar();  // hp visible
        if (tid < H_) {
            float hr = hp_lds[tid] + bhr;
            float hz = hp_lds[H_ + tid] + bhz;
            float hn = hp_lds[2 * H_ + tid] + bhn;
            float r = 1.0f / (1.0f + expf(-(xr + hr)));
            float z = 1.0f / (1.0f + expf(-(xz + hz)));
            float ng = tanhf(xn + r * hn);
            float hnew = (1.0f - z) * ng + z * hown;
            hown = hnew;
            h_lds[tid] = hnew;
            rnnb[(size_t)t * H_ + tid] = hnew;   // fire-and-forget
            xr = nxr; xz = nxz; xn = nxn;
        }
        ldsbar();  // h visible for next matvec
    }
}

// ---------------------------------------------------------------------------
// C: ti = rnn @ W_ti.T + b_ti ; lgr = rnn @ W_lgr[:, :H].T ; z = relu(att*mask)
// ---------------------------------------------------------------------------
__global__ __launch_bounds__(256) void k_post(
        const float* __restrict__ rnn, const float* __restrict__ wcat,
        const float* __restrict__ b_ti, const int* __restrict__ lens,
        float* __restrict__ ti, float* __restrict__ lgr, float* __restrict__ zr) {
    __shared__ __align__(16) float A_lds[H_ * 72];   // [k][r], stride 72 (28.8 KB)
    __shared__ __align__(16) float W_lds[H_ * 112];  // [k][j], stride 112 (44.8 KB)

    int tid = threadIdx.x;
    int base = blockIdx.x * 64;

    for (int idx = tid; idx < 64 * H_; idx += 256) {
        int r = idx / H_, k = idx - r * H_;
        A_lds[k * 72 + r] = rnn[(size_t)(base + r) * H_ + k];
    }
    for (int idx = tid; idx < H_ * 104; idx += 256) {
        int k = idx / 104, jj = idx - k * 104;
        W_lds[k * 112 + jj] = wcat[idx];
    }
    __syncthreads();

    if (tid < 64) {
        float ss = 0.f, sm = 0.f;
        for (int k = 0; k < H_; ++k) {
            float v = A_lds[k * 72 + tid];
            ss = fmaf(v, v, ss); sm += v;
        }
        int row = base + tid;
        int bb = row >> 9, tt = row & 511;
        float att = sm / (fmaxf(sqrtf(ss), 1e-12f) * 1000.0f);  // / (norm * sqrt(H) * H)
        zr[row] = (tt < lens[bb]) ? fmaxf(att, 0.0f) : 0.0f;
    }

    int c = tid % 32, g = tid / 32;
    float4 acc[8];
#pragma unroll
    for (int i = 0; i < 8; ++i) acc[i] = make_float4(0.f, 0.f, 0.f, 0.f);

    if (c < 26) {
        for (int k = 0; k < H_; ++k) {
            float4 wv = *(const float4*)&W_lds[k * 112 + c * 4];
            float4 a0 = *(const float4*)&A_lds[k * 72 + g * 8];
            float4 a1 = *(const float4*)&A_lds[k * 72 + g * 8 + 4];
            fma4(acc[0], a0.x, wv); fma4(acc[1], a0.y, wv);
            fma4(acc[2], a0.z, wv); fma4(acc[3], a0.w, wv);
            fma4(acc[4], a1.x, wv); fma4(acc[5], a1.y, wv);
            fma4(acc[6], a1.z, wv); fma4(acc[7], a1.w, wv);
        }
    }

    if (c < 25) {
        float4 bv = *(const float4*)&b_ti[c * 4];
#pragma unroll
        for (int rr = 0; rr < 8; ++rr) {
            int row = base + g * 8 + rr;
            float4 res;
            res.x = acc[rr].x + bv.x; res.y = acc[rr].y + bv.y;
            res.z = acc[rr].z + bv.z; res.w = acc[rr].w + bv.w;
            *(float4*)&ti[(size_t)row * H_ + c * 4] = res;
        }
    } else if (c == 25) {
#pragma unroll
        for (int rr = 0; rr < 8; ++rr) {
            int row = base + g * 8 + rr;
            lgr[row] = acc[rr].x;  // j == 100 column
        }
    }
}

// ---------------------------------------------------------------------------
// D: rec scan + final GEMV. 1 block per batch row, 128 threads (2 waves).
// W_ts in LDS ([100][RSTR], 43.2 KB, conflict-free stride) -> per-thread
// registers ~20. Gate dot wl·s pipelined via shfl_xor + parity red[]; ONE
// light barrier/step (state double-buffered).
// ---------------------------------------------------------------------------
__global__ __launch_bounds__(128, 1)
void k_rec(
        const float* __restrict__ ti, const float* __restrict__ lgr,
        const float* __restrict__ zr,
        const float* __restrict__ W_ts, const float* __restrict__ b_ts,
        const float* __restrict__ W_lgr, const float* __restrict__ b_lgr,
        const float* __restrict__ W_out, const float* __restrict__ b_out,
        float* __restrict__ out) {
    __shared__ __align__(16) float Wl[H_ * RSTR];   // 43.2 KB
    __shared__ __align__(16) float sA[104];
    __shared__ __align__(16) float sB[104];
    __shared__ float red[2][2];   // [parity][wave]

    int tid = threadIdx.x;
    int b = blockIdx.x;
    int wave = tid >> 6;

    // stage W_ts -> LDS (2500 float4)
    for (int idx = tid; idx < 2500; idx += 128) {
        int j = idx / 25, q = idx - j * 25;
        float4 v = ((const float4*)(W_ts + (size_t)j * H_))[q];
        *(float4*)&Wl[j * RSTR + q * 4] = v;
    }

    float bts = 0.f, wlj = 0.f;
    if (tid < H_) { bts = b_ts[tid]; wlj = W_lgr[H_ + tid]; }
    float blg = b_lgr[0];
    if (tid < 104) sA[tid] = 0.0f;
    if (tid < 4) ((float*)red)[tid] = 0.0f;
    float sown = 0.0f;

    size_t rb = (size_t)b * T_;
    float tiv = 0.f, zt = 0.f, lt = 0.f;
    if (tid < H_) tiv = ti[rb * H_ + tid];
    zt = zr[rb]; lt = lgr[rb];
    __syncthreads();

    const float* wr = &Wl[tid * RSTR];
    float* rd = sA;
    float* wrb = sB;
    for (int t = 0; t < T_; ++t) {
        float sv = 0.f;
        if (tid < H_) {
            float a0 = 0.f, a1 = 0.f, a2 = 0.f, a3 = 0.f;
#pragma unroll
            for (int q = 0; q < 25; ++q) {
                float4 wv = *(const float4*)&wr[q * 4];     // conflict-free
                float4 s4 = *(const float4*)&rd[q * 4];     // broadcast
                a0 = fmaf(wv.x, s4.x, a0); a1 = fmaf(wv.y, s4.y, a1);
                a2 = fmaf(wv.z, s4.z, a2); a3 = fmaf(wv.w, s4.w, a3);
            }
            sv = (a0 + a1) + (a2 + a3);
        }
        // prefetch next step's inputs (stay in flight across the barrier)
        float ntiv = 0.f, nzt = 0.f, nlt = 0.f;
        if (t + 1 < T_) {
            if (tid < H_) ntiv = ti[(rb + t + 1) * H_ + tid];
            nzt = zr[rb + t + 1]; nlt = lgr[rb + t + 1];
        }
        float dot = red[t & 1][0] + red[t & 1][1];
        float part = 0.0f;
        if (tid < H_) {
            float gate = 1.0f / (1.0f + expf(-(lt + dot + blg)));
            float ns = tanhf(tiv + gate * sv + bts);
            float snew = (1.0f - zt) * sown + zt * ns;
            sown = snew;
            wrb[tid] = snew;
            part = wlj * snew;   // partial of NEXT step's gate dot
        }
        tiv = ntiv; zt = nzt; lt = nlt;
#pragma unroll
        for (int off = 1; off < 64; off <<= 1) part += __shfl_xor(part, off, 64);
        if ((tid & 63) == 0) red[(t + 1) & 1][wave] = part;
        ldsbar();  // state + red visible
        float* tmp = rd; rd = wrb; wrb = tmp;
    }

    if (tid < NC_) {
        float o = b_out[tid];
        for (int k = 0; k < H_; ++k) o = fmaf(rd[k], W_out[tid * H_ + k], o);
        out[b * NC_ + tid] = o;
    }
}

// ---------------------------------------------------------------------------
extern "C" void kernel_launch(void* const* d_in, const int* in_sizes, int n_in,
                              void* d_out, int out_size, void* d_ws, size_t ws_size,
                              hipStream_t stream) {
    const int*   txt   = (const int*)d_in[0];
    const int*   lens  = (const int*)d_in[1];
    const float* emb   = (const float*)d_in[2];
    const float* W_ih  = (const float*)d_in[3];
    const float* W_hh  = (const float*)d_in[4];
    const float* b_ih  = (const float*)d_in[5];
    const float* b_hh  = (const float*)d_in[6];
    const float* W_lgr = (const float*)d_in[7];
    const float* b_lgr = (const float*)d_in[8];
    const float* W_ts  = (const float*)d_in[9];
    const float* b_ts  = (const float*)d_in[10];
    const float* W_ti  = (const float*)d_in[11];
    const float* b_ti  = (const float*)d_in[12];
    const float* W_out = (const float*)d_in[13];
    const float* b_out = (const float*)d_in[14];

    float* ws   = (float*)d_ws;
    float* xp   = ws;                    // 39,321,600 floats (157 MB)
    float* rnn  = xp + 39321600;         // 13,107,200 floats (52 MB)
    float* lgrv = rnn + 13107200;        // 131,072
    float* zrv  = lgrv + 131072;         // 131,072
    float* wT   = zrv + 131072;          // 60,000
    float* wcat = wT + 60000;            // 10,400
    float* ti   = xp;                    // reuse xp region after GRU

    float* out = (float*)d_out;

    k_pack<<<276, 256, 0, stream>>>(W_ih, W_ti, W_lgr, wT, wcat);
    k_embgemm<<<4096, 320, 0, stream>>>(txt, emb, wT, b_ih, xp);
    k_gru<<<256, 320, 0, stream>>>(xp, W_hh, b_hh, rnn);
    k_post<<<2048, 256, 0, stream>>>(rnn, wcat, b_ti, lens, ti, lgrv, zrv);
    k_rec<<<256, 128, 0, stream>>>(ti, lgrv, zrv, W_ts, b_ts, W_lgr, b_lgr,
                                   W_out, b_out, out);
}